// Round 3
// baseline (149.681 us; speedup 1.0000x reference)
//
#include <hip/hip_runtime.h>

#define F        128
#define NN       768
#define KE       192          // effective RBF range: d<=17.33 -> centers >=19.2 are dead
#define E_STRIDE 200          // elems; 400 B stride ≡ 16 mod 128 -> conflict-free b128 reads
#define H_STRIDE 136          // elems; 272 B stride ≡ 16 mod 128
#define NT       48           // number of 16-row tiles
#define NBLK     (NT*(NT+1)/2)   // 1176 upper-triangular tile pairs

#define L2E 1.44269504f
#define LN2 0.69314718f

typedef __attribute__((ext_vector_type(8))) short short8;
typedef __attribute__((ext_vector_type(4))) float floatx4;

__device__ __forceinline__ unsigned short f2bf(float f) {
    union { float f; unsigned u; } v; v.f = f;
    return (unsigned short)((v.u + 0x8000u) >> 16);   // round-half-up (2 VALU)
}

// ssp(z) = softplus(z) - ln2 = ln2*(log2(1 + 2^(z*log2e)) - 1); inputs bounded -> no overflow path
__device__ __forceinline__ float ssp_zl(float zl2e) {
    float t = exp2f(zl2e);                  // v_exp_f32
    float u = __log2f(1.0f + t);            // v_add + v_log_f32
    return fmaf(LN2, u, -LN2);
}

// Pack W1[0:192][128] and W2[128][128] (f32) into bf16 MFMA B-fragment order:
// elem idx = ((ks*8 + nt)*64 + lane)*8 + t ; k = ks*32 + (lane>>4)*8 + t ; n = nt*16 + (lane&15)
__global__ void prep_w(const float* __restrict__ W1, const float* __restrict__ W2,
                       unsigned short* __restrict__ W1s, unsigned short* __restrict__ W2s) {
    int idx = blockIdx.x * 256 + threadIdx.x;          // 40960 total
    if (idx < KE * F) {                                // 24576
        int t = idx & 7, lane = (idx >> 3) & 63, frag = idx >> 9;   // frag 0..47
        int k = (frag >> 3) * 32 + (lane >> 4) * 8 + t;             // < 192
        int n = (frag & 7) * 16 + (lane & 15);
        W1s[idx] = f2bf(W1[k * F + n]);
    } else {
        int j = idx - KE * F;                          // < 16384
        int t = j & 7, lane = (j >> 3) & 63, frag = j >> 9;         // frag 0..31
        int k = (frag >> 3) * 32 + (lane >> 4) * 8 + t;             // < 128
        int n = (frag & 7) * 16 + (lane & 15);
        W2s[j] = f2bf(W2[k * F + n]);
    }
}

__global__ __launch_bounds__(256, 3) void cfconv_main(
    const float* __restrict__ x, const float* __restrict__ r,
    const float* __restrict__ b1, const float* __restrict__ b2,
    const unsigned short* __restrict__ W1s, const unsigned short* __restrict__ W2s,
    float* __restrict__ out)
{
    __shared__ __align__(16) unsigned short e_lds[64 * E_STRIDE];  // 25600 B
    __shared__ __align__(16) unsigned short h_lds[64 * H_STRIDE];  // 17408 B
    __shared__ float d_all[256];
    __shared__ int   klo_all[256];

    const int tid  = threadIdx.x;
    const int lane = tid & 63;
    const int wave = tid >> 6;
    const int quad = lane >> 4;
    const int l15  = lane & 15;

    // ---- decode upper-triangular tile pair (A <= B); f(A) = A*(97-A)/2 ----
    int b = blockIdx.x;
    int A = (int)((97.0f - sqrtf(9409.0f - 8.0f * (float)b)) * 0.5f);
    while ((A + 1) * (97 - (A + 1)) / 2 <= b) ++A;
    while (A * (97 - A) / 2 > b) --A;
    const int B = A + (b - A * (97 - A) / 2);
    const int Ai0 = A * 16, Bj0 = B * 16;
    const bool diag = (A == B);

    // ---- hoist ALL B-fragments into VGPRs (loop-invariant across the 4 s-iters) ----
    short8 w1f[6][2], w2f[4][2];
    #pragma unroll
    for (int ks = 0; ks < KE / 32; ++ks) {
        w1f[ks][0] = *(const short8*)&W1s[((ks*8 + wave*2 + 0) * 64 + lane) * 8];
        w1f[ks][1] = *(const short8*)&W1s[((ks*8 + wave*2 + 1) * 64 + lane) * 8];
    }
    #pragma unroll
    for (int ks = 0; ks < F / 32; ++ks) {
        w2f[ks][0] = *(const short8*)&W2s[((ks*8 + wave*2 + 0) * 64 + lane) * 8];
        w2f[ks][1] = *(const short8*)&W2s[((ks*8 + wave*2 + 1) * 64 + lane) * 8];
    }

    // ---- distances + window starts for all 256 (ii,jj) pairs ----
    {
        int p = tid;
        int gi = Ai0 + (p >> 4), gj = Bj0 + (p & 15);
        float dx = r[gi*3+0] - r[gj*3+0];
        float dy = r[gi*3+1] - r[gj*3+1];
        float dz = r[gi*3+2] - r[gj*3+2];
        float sq = dx*dx + dy*dy + dz*dz;
        float d  = sq > 0.0f ? sqrtf(sq) : 0.0f;
        d_all[p] = d;
        int klo = (int)ceilf(d * 10.0f - 13.0f);   // |d - 0.1k| > 1.3 -> e < 5e-8
        klo &= ~1;                                 // even -> b16 lane pairs share a dword
        klo = klo < 0 ? 0 : (klo > KE - 32 ? KE - 32 : klo);
        klo_all[p] = klo;
    }

    // ---- one-time zero of the E tile (per-s stale-window clears replace full refills) ----
    {
        short8 z = 0;
        short8* p8 = (short8*)e_lds;
        for (int c = tid; c < (64 * E_STRIDE) / 8; c += 256) p8[c] = z;
    }

    const int c0 = wave * 32 + l15;                // this wave's column strip
    const int c1 = c0 + 16;
    const float b1L0 = b1[c0] * L2E, b1L1 = b1[c1] * L2E;   // bias pre-scaled to log2 domain
    const float b2L0 = b2[c0] * L2E, b2L1 = b2[c1] * L2E;

    // x rows of the B tile, indexed by this thread's quad: jj = quad*4 + rg
    float xB0[4], xB1[4];
    #pragma unroll
    for (int rg = 0; rg < 4; ++rg) {
        int gj = Bj0 + quad * 4 + rg;
        xB0[rg] = x[gj * F + c0];
        xB1[rg] = x[gj * F + c1];
    }
    float oB0[4] = {0,0,0,0}, oB1[4] = {0,0,0,0};

    const int rq16 = 16 * ((l15 >> 2) & 3);        // h-swizzle offset for A-frag reads

    __syncthreads();

    for (int s = 0; s < 4; ++s) {
        // ---- clear stale windows + fill new ones: one half-wave (32 lanes) per row.
        //      clear & fill of a row come from the SAME wave -> DS ops ordered; rows
        //      never alias across waves -> no barrier needed between clear and fill.
        {
            int kl = lane & 31;
            for (int rr = wave * 2 + (lane >> 5); rr < 64; rr += 8) {
                if (s > 0)
                    e_lds[rr * E_STRIDE + klo_all[(s-1)*64 + rr] + kl] = 0;
                int p = s * 64 + rr;
                float d = d_all[p];
                int k = klo_all[p] + kl;           // < 192 always
                float t = fmaf(-0.1f, (float)k, d);
                float e = exp2f(t * t * (-10.0f * L2E));
                e_lds[rr * E_STRIDE + k] = f2bf(e);
            }
        }
        __syncthreads();

        // ---- GEMM1: E[64 x 192] @ W1(regs) ----
        floatx4 acc[4][2];
        #pragma unroll
        for (int mt = 0; mt < 4; ++mt) { acc[mt][0] = 0; acc[mt][1] = 0; }
        #pragma unroll
        for (int ks = 0; ks < KE / 32; ++ks) {
            short8 af[4];
            #pragma unroll
            for (int mt = 0; mt < 4; ++mt)
                af[mt] = *(const short8*)&e_lds[(mt*16 + l15) * E_STRIDE + ks*32 + quad*8];
            #pragma unroll
            for (int mt = 0; mt < 4; ++mt) {
                acc[mt][0] = __builtin_amdgcn_mfma_f32_16x16x32_bf16(af[mt], w1f[ks][0], acc[mt][0], 0, 0, 0);
                acc[mt][1] = __builtin_amdgcn_mfma_f32_16x16x32_bf16(af[mt], w1f[ks][1], acc[mt][1], 0, 0, 0);
            }
        }

        // ---- epilogue 1: h = ssp(acc + b1) -> swizzled LDS (conflict-free quad writes) ----
        #pragma unroll
        for (int mt = 0; mt < 4; ++mt) {
            #pragma unroll
            for (int rg = 0; rg < 4; ++rg) {
                int row = mt*16 + quad*4 + rg;     // (row>>2)&3 == quad
                float h0 = ssp_zl(fmaf(acc[mt][0][rg], L2E, b1L0));
                float h1 = ssp_zl(fmaf(acc[mt][1][rg], L2E, b1L1));
                h_lds[row * H_STRIDE + ((c0 + 16*quad) & 127)] = f2bf(h0);
                h_lds[row * H_STRIDE + ((c1 + 16*quad) & 127)] = f2bf(h1);
            }
        }
        __syncthreads();

        // ---- GEMM2: h[64 x 128] @ W2(regs) ----
        floatx4 acc2[4][2];
        #pragma unroll
        for (int mt = 0; mt < 4; ++mt) { acc2[mt][0] = 0; acc2[mt][1] = 0; }
        #pragma unroll
        for (int ks = 0; ks < F / 32; ++ks) {
            int ko = (ks*32 + quad*8 + rq16) & 127;
            short8 af[4];
            #pragma unroll
            for (int mt = 0; mt < 4; ++mt)
                af[mt] = *(const short8*)&h_lds[(mt*16 + l15) * H_STRIDE + ko];
            #pragma unroll
            for (int mt = 0; mt < 4; ++mt) {
                acc2[mt][0] = __builtin_amdgcn_mfma_f32_16x16x32_bf16(af[mt], w2f[ks][0], acc2[mt][0], 0, 0, 0);
                acc2[mt][1] = __builtin_amdgcn_mfma_f32_16x16x32_bf16(af[mt], w2f[ks][1], acc2[mt][1], 0, 0, 0);
            }
        }

        // ---- epilogue 2: w = ssp(acc2 + b2); o_A += xB*w ; o_B += xA*w ----
        float xA0[4], xA1[4];
        #pragma unroll
        for (int mt = 0; mt < 4; ++mt) {
            int gi = Ai0 + s*4 + mt;
            xA0[mt] = x[gi * F + c0];
            xA1[mt] = x[gi * F + c1];
        }
        float oA0[4] = {0,0,0,0}, oA1[4] = {0,0,0,0};
        #pragma unroll
        for (int mt = 0; mt < 4; ++mt) {
            #pragma unroll
            for (int rg = 0; rg < 4; ++rg) {
                float w0 = ssp_zl(fmaf(acc2[mt][0][rg], L2E, b2L0));
                float w1 = ssp_zl(fmaf(acc2[mt][1][rg], L2E, b2L1));
                oA0[mt] = fmaf(xB0[rg], w0, oA0[mt]);
                oA1[mt] = fmaf(xB1[rg], w1, oA1[mt]);
                if (!diag) {
                    oB0[rg] = fmaf(xA0[mt], w0, oB0[rg]);
                    oB1[rg] = fmaf(xA1[mt], w1, oB1[rg]);
                }
            }
        }
        // reduce o_A across quads (rows complete within this sub-tile) and scatter
        #pragma unroll
        for (int mt = 0; mt < 4; ++mt) {
            oA0[mt] += __shfl_xor(oA0[mt], 16, 64); oA0[mt] += __shfl_xor(oA0[mt], 32, 64);
            oA1[mt] += __shfl_xor(oA1[mt], 16, 64); oA1[mt] += __shfl_xor(oA1[mt], 32, 64);
        }
        if (lane < 16) {
            #pragma unroll
            for (int mt = 0; mt < 4; ++mt) {
                int gi = Ai0 + s*4 + mt;
                atomicAdd(&out[gi * F + c0], oA0[mt]);
                atomicAdd(&out[gi * F + c1], oA1[mt]);
            }
        }
    }

    // ---- scatter o_B (complete over all ii; one owner-thread per (jj,col)) ----
    if (!diag) {
        #pragma unroll
        for (int rg = 0; rg < 4; ++rg) {
            int gj = Bj0 + quad * 4 + rg;
            atomicAdd(&out[gj * F + c0], oB0[rg]);
            atomicAdd(&out[gj * F + c1], oB1[rg]);
        }
    }
}

extern "C" void kernel_launch(void* const* d_in, const int* in_sizes, int n_in,
                              void* d_out, int out_size, void* d_ws, size_t ws_size,
                              hipStream_t stream) {
    const float* x  = (const float*)d_in[0];
    const float* r  = (const float*)d_in[1];
    const float* W1 = (const float*)d_in[2];
    const float* b1 = (const float*)d_in[3];
    const float* W2 = (const float*)d_in[4];
    const float* b2 = (const float*)d_in[5];
    float* out = (float*)d_out;

    unsigned short* W1s = (unsigned short*)d_ws;       // 24576 bf16
    unsigned short* W2s = W1s + KE * F;                // 16384 bf16

    hipMemsetAsync(d_out, 0, (size_t)out_size * sizeof(float), stream);
    prep_w<<<160, 256, 0, stream>>>(W1, W2, W1s, W2s);
    cfconv_main<<<NBLK, 256, 0, stream>>>(x, r, b1, b2, W1s, W2s, out);
}

// Round 4
// 128.598 us; speedup vs baseline: 1.1639x; 1.1639x over previous
//
#include <hip/hip_runtime.h>

#define F        128
#define NN       768
#define KE       192          // effective RBF range: d<=17.33 -> centers >=19.2 are dead
#define E_STRIDE 200          // elems; 400 B stride ≡ 16 mod 128 -> conflict-free b128 reads
#define H_STRIDE 136          // elems; 272 B stride ≡ 16 mod 128
#define NT       48           // number of 16-row tiles
#define NBLK     (NT*(NT+1)/2)   // 1176 upper-triangular tile pairs

#define L2E 1.44269504f
#define LN2 0.69314718f

typedef __attribute__((ext_vector_type(8))) short short8;
typedef __attribute__((ext_vector_type(4))) float floatx4;

__device__ __forceinline__ unsigned short f2bf(float f) {
    union { float f; unsigned u; } v; v.f = f;
    return (unsigned short)((v.u + 0x8000u) >> 16);   // round-half-up (2 VALU)
}

// ssp(z) = softplus(z) - ln2 = ln2*(log2(1 + 2^(z*log2e)) - 1); inputs bounded -> no overflow path
__device__ __forceinline__ float ssp_zl(float zl2e) {
    float t = exp2f(zl2e);                  // v_exp_f32
    float u = __log2f(1.0f + t);            // v_add + v_log_f32
    return fmaf(LN2, u, -LN2);
}

// opaque pin: compiler can no longer rematerialize/sink the loaded value
__device__ __forceinline__ void pin(short8& v) { asm volatile("" : "+v"(v)); }

// Pack W1[0:192][128] and W2[128][128] (f32) into bf16 MFMA B-fragment order,
// and zero the output buffer (replaces a separate hipMemsetAsync node).
// elem idx = ((ks*8 + nt)*64 + lane)*8 + t ; k = ks*32 + (lane>>4)*8 + t ; n = nt*16 + (lane&15)
__global__ void prep_w(const float* __restrict__ W1, const float* __restrict__ W2,
                       unsigned short* __restrict__ W1s, unsigned short* __restrict__ W2s,
                       float* __restrict__ out) {
    int idx = blockIdx.x * 256 + threadIdx.x;          // grid covers 98304 = NN*F
    out[idx] = 0.0f;
    if (idx < KE * F) {                                // 24576
        int t = idx & 7, lane = (idx >> 3) & 63, frag = idx >> 9;   // frag 0..47
        int k = (frag >> 3) * 32 + (lane >> 4) * 8 + t;             // < 192
        int n = (frag & 7) * 16 + (lane & 15);
        W1s[idx] = f2bf(W1[k * F + n]);
    } else if (idx < KE * F + F * F) {                 // next 16384
        int j = idx - KE * F;
        int t = j & 7, lane = (j >> 3) & 63, frag = j >> 9;         // frag 0..31
        int k = (frag >> 3) * 32 + (lane >> 4) * 8 + t;             // < 128
        int n = (frag & 7) * 16 + (lane & 15);
        W2s[j] = f2bf(W2[k * F + n]);
    }
}

__global__ __launch_bounds__(256, 2) void cfconv_main(
    const float* __restrict__ x, const float* __restrict__ r,
    const float* __restrict__ b1, const float* __restrict__ b2,
    const unsigned short* __restrict__ W1s, const unsigned short* __restrict__ W2s,
    float* __restrict__ out)
{
    __shared__ __align__(16) unsigned short e_lds[64 * E_STRIDE];  // 25600 B
    __shared__ __align__(16) unsigned short h_lds[64 * H_STRIDE];  // 17408 B
    __shared__ float d_all[256];
    __shared__ int   klo_all[256];

    const int tid  = threadIdx.x;
    const int lane = tid & 63;
    const int wave = tid >> 6;
    const int quad = lane >> 4;
    const int l15  = lane & 15;

    // ---- decode upper-triangular tile pair (A <= B); f(A) = A*(97-A)/2 ----
    int b = blockIdx.x;
    int A = (int)((97.0f - sqrtf(9409.0f - 8.0f * (float)b)) * 0.5f);
    while ((A + 1) * (97 - (A + 1)) / 2 <= b) ++A;
    while (A * (97 - A) / 2 > b) --A;
    const int B = A + (b - A * (97 - A) / 2);
    const int Ai0 = A * 16, Bj0 = B * 16;
    const bool diag = (A == B);

    // ---- hoist ALL B-fragments into VGPRs (invariant across the 4 s-iters) and PIN them ----
    short8 w1f[6][2], w2f[4][2];
    #pragma unroll
    for (int ks = 0; ks < KE / 32; ++ks) {
        w1f[ks][0] = *(const short8*)&W1s[((ks*8 + wave*2 + 0) * 64 + lane) * 8];
        w1f[ks][1] = *(const short8*)&W1s[((ks*8 + wave*2 + 1) * 64 + lane) * 8];
    }
    #pragma unroll
    for (int ks = 0; ks < F / 32; ++ks) {
        w2f[ks][0] = *(const short8*)&W2s[((ks*8 + wave*2 + 0) * 64 + lane) * 8];
        w2f[ks][1] = *(const short8*)&W2s[((ks*8 + wave*2 + 1) * 64 + lane) * 8];
    }
    #pragma unroll
    for (int ks = 0; ks < 6; ++ks) { pin(w1f[ks][0]); pin(w1f[ks][1]); }
    #pragma unroll
    for (int ks = 0; ks < 4; ++ks) { pin(w2f[ks][0]); pin(w2f[ks][1]); }

    // ---- distances + window starts for all 256 (ii,jj) pairs ----
    {
        int p = tid;
        int gi = Ai0 + (p >> 4), gj = Bj0 + (p & 15);
        float dx = r[gi*3+0] - r[gj*3+0];
        float dy = r[gi*3+1] - r[gj*3+1];
        float dz = r[gi*3+2] - r[gj*3+2];
        float sq = dx*dx + dy*dy + dz*dz;
        float d  = sq > 0.0f ? sqrtf(sq) : 0.0f;
        d_all[p] = d;
        int klo = (int)ceilf(d * 10.0f - 13.0f);   // |d - 0.1k| > 1.3 -> e < 5e-8
        klo &= ~1;                                 // even -> b16 lane pairs share a dword
        klo = klo < 0 ? 0 : (klo > KE - 32 ? KE - 32 : klo);
        klo_all[p] = klo;
    }

    // ---- one-time zero of the E tile (per-s stale-window clears replace full refills) ----
    {
        short8 z = 0;
        short8* p8 = (short8*)e_lds;
        for (int c = tid; c < (64 * E_STRIDE) / 8; c += 256) p8[c] = z;
    }

    const int c0 = wave * 32 + l15;                // this wave's column strip
    const int c1 = c0 + 16;
    const float b1L0 = b1[c0] * L2E, b1L1 = b1[c1] * L2E;   // bias pre-scaled to log2 domain
    const float b2L0 = b2[c0] * L2E, b2L1 = b2[c1] * L2E;

    // x rows of the B tile, indexed by this thread's quad: jj = quad*4 + rg
    float xB0[4], xB1[4];
    #pragma unroll
    for (int rg = 0; rg < 4; ++rg) {
        int gj = Bj0 + quad * 4 + rg;
        xB0[rg] = x[gj * F + c0];
        xB1[rg] = x[gj * F + c1];
    }
    float oB0[4] = {0,0,0,0}, oB1[4] = {0,0,0,0};

    const int rq16 = 16 * ((l15 >> 2) & 3);        // h-swizzle offset for A-frag reads

    __syncthreads();

    for (int s = 0; s < 4; ++s) {
        // ---- clear stale windows + fill new ones: one half-wave (32 lanes) per row.
        //      clear & fill of a row come from the SAME wave -> DS ops ordered; rows
        //      never alias across waves -> no barrier needed between clear and fill.
        {
            int kl = lane & 31;
            for (int rr = wave * 2 + (lane >> 5); rr < 64; rr += 8) {
                if (s > 0)
                    e_lds[rr * E_STRIDE + klo_all[(s-1)*64 + rr] + kl] = 0;
                int p = s * 64 + rr;
                float d = d_all[p];
                int k = klo_all[p] + kl;           // < 192 always
                float t = fmaf(-0.1f, (float)k, d);
                float e = exp2f(t * t * (-10.0f * L2E));
                e_lds[rr * E_STRIDE + k] = f2bf(e);
            }
        }
        __syncthreads();

        // ---- GEMM1: E[64 x 192] @ W1(regs) ----
        floatx4 acc[4][2];
        #pragma unroll
        for (int mt = 0; mt < 4; ++mt) { acc[mt][0] = 0; acc[mt][1] = 0; }
        #pragma unroll
        for (int ks = 0; ks < KE / 32; ++ks) {
            short8 af[4];
            #pragma unroll
            for (int mt = 0; mt < 4; ++mt)
                af[mt] = *(const short8*)&e_lds[(mt*16 + l15) * E_STRIDE + ks*32 + quad*8];
            #pragma unroll
            for (int mt = 0; mt < 4; ++mt) {
                acc[mt][0] = __builtin_amdgcn_mfma_f32_16x16x32_bf16(af[mt], w1f[ks][0], acc[mt][0], 0, 0, 0);
                acc[mt][1] = __builtin_amdgcn_mfma_f32_16x16x32_bf16(af[mt], w1f[ks][1], acc[mt][1], 0, 0, 0);
            }
        }

        // ---- epilogue 1: h = ssp(acc + b1) -> swizzled LDS (conflict-free quad writes) ----
        #pragma unroll
        for (int mt = 0; mt < 4; ++mt) {
            #pragma unroll
            for (int rg = 0; rg < 4; ++rg) {
                int row = mt*16 + quad*4 + rg;     // (row>>2)&3 == quad
                float h0 = ssp_zl(fmaf(acc[mt][0][rg], L2E, b1L0));
                float h1 = ssp_zl(fmaf(acc[mt][1][rg], L2E, b1L1));
                h_lds[row * H_STRIDE + ((c0 + 16*quad) & 127)] = f2bf(h0);
                h_lds[row * H_STRIDE + ((c1 + 16*quad) & 127)] = f2bf(h1);
            }
        }
        __syncthreads();

        // ---- GEMM2: h[64 x 128] @ W2(regs) ----
        floatx4 acc2[4][2];
        #pragma unroll
        for (int mt = 0; mt < 4; ++mt) { acc2[mt][0] = 0; acc2[mt][1] = 0; }
        #pragma unroll
        for (int ks = 0; ks < F / 32; ++ks) {
            int ko = (ks*32 + quad*8 + rq16) & 127;
            short8 af[4];
            #pragma unroll
            for (int mt = 0; mt < 4; ++mt)
                af[mt] = *(const short8*)&h_lds[(mt*16 + l15) * H_STRIDE + ko];
            #pragma unroll
            for (int mt = 0; mt < 4; ++mt) {
                acc2[mt][0] = __builtin_amdgcn_mfma_f32_16x16x32_bf16(af[mt], w2f[ks][0], acc2[mt][0], 0, 0, 0);
                acc2[mt][1] = __builtin_amdgcn_mfma_f32_16x16x32_bf16(af[mt], w2f[ks][1], acc2[mt][1], 0, 0, 0);
            }
        }

        // ---- epilogue 2: w = ssp(acc2 + b2); o_A += xB*w ; o_B += xA*w ----
        float xA0[4], xA1[4];
        #pragma unroll
        for (int mt = 0; mt < 4; ++mt) {
            int gi = Ai0 + s*4 + mt;
            xA0[mt] = x[gi * F + c0];
            xA1[mt] = x[gi * F + c1];
        }
        float oA0[4] = {0,0,0,0}, oA1[4] = {0,0,0,0};
        #pragma unroll
        for (int mt = 0; mt < 4; ++mt) {
            #pragma unroll
            for (int rg = 0; rg < 4; ++rg) {
                float w0 = ssp_zl(fmaf(acc2[mt][0][rg], L2E, b2L0));
                float w1 = ssp_zl(fmaf(acc2[mt][1][rg], L2E, b2L1));
                oA0[mt] = fmaf(xB0[rg], w0, oA0[mt]);
                oA1[mt] = fmaf(xB1[rg], w1, oA1[mt]);
                if (!diag) {
                    oB0[rg] = fmaf(xA0[mt], w0, oB0[rg]);
                    oB1[rg] = fmaf(xA1[mt], w1, oB1[rg]);
                }
            }
        }
        // reduce o_A across quads (rows complete within this sub-tile) and scatter
        #pragma unroll
        for (int mt = 0; mt < 4; ++mt) {
            oA0[mt] += __shfl_xor(oA0[mt], 16, 64); oA0[mt] += __shfl_xor(oA0[mt], 32, 64);
            oA1[mt] += __shfl_xor(oA1[mt], 16, 64); oA1[mt] += __shfl_xor(oA1[mt], 32, 64);
        }
        if (lane < 16) {
            #pragma unroll
            for (int mt = 0; mt < 4; ++mt) {
                int gi = Ai0 + s*4 + mt;
                atomicAdd(&out[gi * F + c0], oA0[mt]);
                atomicAdd(&out[gi * F + c1], oA1[mt]);
            }
        }
    }

    // ---- scatter o_B (complete over all ii; one owner-thread per (jj,col)) ----
    if (!diag) {
        #pragma unroll
        for (int rg = 0; rg < 4; ++rg) {
            int gj = Bj0 + quad * 4 + rg;
            atomicAdd(&out[gj * F + c0], oB0[rg]);
            atomicAdd(&out[gj * F + c1], oB1[rg]);
        }
    }
}

extern "C" void kernel_launch(void* const* d_in, const int* in_sizes, int n_in,
                              void* d_out, int out_size, void* d_ws, size_t ws_size,
                              hipStream_t stream) {
    const float* x  = (const float*)d_in[0];
    const float* r  = (const float*)d_in[1];
    const float* W1 = (const float*)d_in[2];
    const float* b1 = (const float*)d_in[3];
    const float* W2 = (const float*)d_in[4];
    const float* b2 = (const float*)d_in[5];
    float* out = (float*)d_out;

    unsigned short* W1s = (unsigned short*)d_ws;       // 24576 bf16
    unsigned short* W2s = W1s + KE * F;                // 16384 bf16

    prep_w<<<(NN * F) / 256, 256, 0, stream>>>(W1, W2, W1s, W2s, out);  // pack + zero out
    cfconv_main<<<NBLK, 256, 0, stream>>>(x, r, b1, b2, W1s, W2s, out);
}